// Round 7
// baseline (284.838 us; speedup 1.0000x reference)
//
#include <hip/hip_runtime.h>
#include <hip/hip_bf16.h>
#include <stdint.h>

// Problem dims
#define NE 8
#define NT 1024
#define NH 2048
#define NI 1408
#define NI2 (2 * NI)  // 2816

typedef __attribute__((ext_vector_type(8))) short          bf16x8;
typedef __attribute__((ext_vector_type(8))) unsigned short u16x8;
typedef __attribute__((ext_vector_type(4))) unsigned short u16x4;
typedef __attribute__((ext_vector_type(4))) float          f32x4;

__device__ __forceinline__ unsigned short f2bf(float f) {
  union { float f; uint32_t u; } v; v.f = f;
  uint32_t u = v.u;
  return (unsigned short)((u + 0x7FFFu + ((u >> 16) & 1u)) >> 16);  // RNE
}

// async global->LDS, 16B per lane. LDS dest is wave-uniform base + lane*16.
__device__ __forceinline__ void gload_lds16(const void* g, void* l) {
  __builtin_amdgcn_global_load_lds(
      (const __attribute__((address_space(1))) uint32_t*)g,
      (__attribute__((address_space(3))) uint32_t*)l, 16, 0, 0);
}

#define WAITV(n) asm volatile("s_waitcnt vmcnt(" #n ")" ::: "memory")
#define BAR() do { __builtin_amdgcn_sched_barrier(0); \
                   __builtin_amdgcn_s_barrier();      \
                   __builtin_amdgcn_sched_barrier(0); } while (0)

// ---------------------------------------------------------------------------
// x: fp32 -> bf16 elementwise
// ---------------------------------------------------------------------------
__global__ __launch_bounds__(256) void cvt_bf16(const float* __restrict__ src,
                                                unsigned short* __restrict__ dst,
                                                int n8) {
  int i = blockIdx.x * blockDim.x + threadIdx.x;
  const int stride = gridDim.x * blockDim.x;
  for (; i < n8; i += stride) {
    const float4 f0 = ((const float4*)src)[i * 2];
    const float4 f1 = ((const float4*)src)[i * 2 + 1];
    u16x8 o;
    o[0] = f2bf(f0.x); o[1] = f2bf(f0.y); o[2] = f2bf(f0.z); o[3] = f2bf(f0.w);
    o[4] = f2bf(f1.x); o[5] = f2bf(f1.y); o[6] = f2bf(f1.z); o[7] = f2bf(f1.w);
    ((u16x8*)dst)[i] = o;
  }
}

// ---------------------------------------------------------------------------
// Transpose + cvt:  src [E][R][C] f32  ->  dst rows mapped from c, ld = R, bf16
// ilv=1: out row = ((c>>4)<<5) | (c&15) | radd   (16-col gate/up interleave)
// ---------------------------------------------------------------------------
__global__ __launch_bounds__(256) void transpose_cvt(
    const float* __restrict__ src, unsigned short* __restrict__ dst,
    int R, int C, long estride, int ilv, int radd) {
  __shared__ float tile[64][65];
  const int e  = blockIdx.z;
  const int c0 = blockIdx.x * 64;
  const int r0 = blockIdx.y * 64;
  const float* s = src + (size_t)e * R * C;
  unsigned short* d = dst + (size_t)e * estride;
  const int tid = threadIdx.x;
  const int tr  = tid >> 4;        // 0..15
  const int tc  = (tid & 15) * 4;  // 0..60
  #pragma unroll
  for (int it = 0; it < 4; ++it) {
    const int r = it * 16 + tr;
    float4 v = *(const float4*)(s + (size_t)(r0 + r) * C + c0 + tc);
    tile[r][tc + 0] = v.x; tile[r][tc + 1] = v.y;
    tile[r][tc + 2] = v.z; tile[r][tc + 3] = v.w;
  }
  __syncthreads();
  #pragma unroll
  for (int it = 0; it < 4; ++it) {
    const int oc = it * 16 + tr;
    const int c  = c0 + oc;
    const int ro = ilv ? ((((c >> 4) << 5) | (c & 15)) | radd) : c;
    u16x4 o;
    o[0] = f2bf(tile[tc + 0][oc]);
    o[1] = f2bf(tile[tc + 1][oc]);
    o[2] = f2bf(tile[tc + 2][oc]);
    o[3] = f2bf(tile[tc + 3][oc]);
    *(u16x4*)(d + (size_t)ro * R + r0 + tc) = o;
  }
}

// ---------------------------------------------------------------------------
// m201-faithful 8-phase GEMM: C[e,m,n] = A[e,m,:] . B[e,n,:]  (bf16, K-contig)
// BM=BN=256, BK=64; 512 thr (8 waves 2Mx4N, wave tile 128x64).
// LDS 128 KiB = 2 dbuf x {A,B} x 2 half-tiles x (128 rows x 64 K).
// Half-group (4 phases) computing tile t from buf:
//   P1: ds a0(8)+b0(4); stage (t+1):A-ht0 -> buf^1 | BAR | 16 MFMA | BAR
//   P2: ds b1(4);       stage (t+1):A-ht1 -> buf^1 | BAR | 16 MFMA | BAR
//   P3: ds a1(8);       stage (t+2):B-ht0 -> buf   | BAR | 16 MFMA | BAR
//   P4:                 stage (t+2):B-ht1 -> buf   | BAR | 16 MFMA | vmcnt(4) | BAR
// Stage stream runs 3 phases ahead of its covering vmcnt(4) (2 ht in flight);
// never vmcnt(0) in the loop. Epilogue: clamp staged tile idx (dead slots).
// T2 XOR-swizzle via pre-swizzled global source; T5 setprio; T1 XCD chunks.
// MODE 0: f32 out [E][1024][NBY*256]
// MODE 1: silu-pair bf16 out [E][1024][NBY*128] (B rows interleaved g16/u16)
// ---------------------------------------------------------------------------
template <int NBY, int KDIM, int MODE>
__global__ __launch_bounds__(512, 2) void gemm_8ph(
    const unsigned short* __restrict__ Ag,  // [E][1024][KDIM]
    const unsigned short* __restrict__ Bg,  // [E][NBY*256][KDIM]
    void* __restrict__ outp) {
  constexpr int KT    = KDIM / 64;  // even
  constexpr int CHUNK = NBY * 4;    // blocks per XCD = one expert

  __shared__ __align__(16) unsigned short As[2][2][128 * 64];
  __shared__ __align__(16) unsigned short Bs[2][2][128 * 64];

  const int flat = blockIdx.x;
  const int orig = (flat & 7) * CHUNK + (flat >> 3);
  const int bx   = orig & 3;
  const int rest = orig >> 2;
  const int by   = rest % NBY;
  const int e    = rest / NBY;

  const int bm  = bx * 256;
  const int bnn = by * 256;

  const int tid  = threadIdx.x;
  const int lane = tid & 63;
  const int w    = tid >> 6;
  const int wrm  = (w >> 2) * 128;  // wave M rows
  const int wcn  = (w & 3) * 64;    // wave N cols
  const int htA  = w >> 2;          // A staging-half this wave reads
  const int htB  = (w & 3) >> 1;    // B staging-half
  const int lcB  = wcn & 127;       // local row base inside B half (0 or 64)

  const unsigned short* Ae = Ag + (size_t)e * 1024 * KDIM;
  const unsigned short* Be = Bg + (size_t)e * (NBY * 256) * KDIM;

  // staging: each half-tile (128 rows x 128B) = 2 gloads; per gload a wave
  // covers 8 rows (w*8 + l8), lane chunk jx pre-swizzled so linear LDS dest
  // equals the XOR-swizzled layout the frag reads expect.
  const int l8 = lane >> 3;
  const int jx = (lane & 7) ^ l8;
  const unsigned short* aA = Ae + (size_t)(bm  + w * 8 + l8) * KDIM + jx * 8;
  const unsigned short* aB = Be + (size_t)(bnn + w * 8 + l8) * KDIM + jx * 8;

  auto SA = [&](int buf, int h, int t) {
    #pragma unroll
    for (int r = 0; r < 2; ++r)
      gload_lds16(aA + (size_t)(h * 128 + r * 64) * KDIM + t * 64,
                  &As[buf][h][(r * 64 + w * 8) * 64]);
  };
  auto SB = [&](int buf, int h, int t) {
    #pragma unroll
    for (int r = 0; r < 2; ++r)
      gload_lds16(aB + (size_t)(h * 128 + r * 64) * KDIM + t * 64,
                  &Bs[buf][h][(r * 64 + w * 8) * 64]);
  };

  f32x4 acc[8][4];
  #pragma unroll
  for (int i = 0; i < 8; ++i)
    #pragma unroll
    for (int j = 0; j < 4; ++j) acc[i][j] = f32x4{0.f, 0.f, 0.f, 0.f};

  // swizzled fragment read offset (bytes) within a 16-row frag; ^64 flips kk
  const int aoff = (lane & 15) * 128 + ((((lane >> 4) << 4)) ^ ((lane & 7) << 4));

  auto HG = [&](int buf, int tA, int tB) {
    const char* LA = (const char*)&As[buf][htA][0];
    const char* LB = (const char*)&Bs[buf][htB][0] + lcB * 128;
    bf16x8 a0[4][2], a1[4][2], b0[2][2], b1[2][2];

    // ---- P1: a0 + b0 reads; stage next-tile A-ht0 into other buf
    #pragma unroll
    for (int mi = 0; mi < 4; ++mi) {
      a0[mi][0] = *(const bf16x8*)(LA + mi * 2048 + aoff);
      a0[mi][1] = *(const bf16x8*)(LA + mi * 2048 + (aoff ^ 64));
    }
    #pragma unroll
    for (int nj = 0; nj < 2; ++nj) {
      b0[nj][0] = *(const bf16x8*)(LB + nj * 2048 + aoff);
      b0[nj][1] = *(const bf16x8*)(LB + nj * 2048 + (aoff ^ 64));
    }
    SA(buf ^ 1, 0, tA);
    BAR();
    __builtin_amdgcn_s_setprio(1);
    #pragma unroll
    for (int kk = 0; kk < 2; ++kk)
      #pragma unroll
      for (int mi = 0; mi < 4; ++mi)
        #pragma unroll
        for (int nj = 0; nj < 2; ++nj)
          acc[mi][nj] = __builtin_amdgcn_mfma_f32_16x16x32_bf16(
              a0[mi][kk], b0[nj][kk], acc[mi][nj], 0, 0, 0);
    __builtin_amdgcn_s_setprio(0);
    BAR();

    // ---- P2: b1 reads; stage next-tile A-ht1
    #pragma unroll
    for (int nj = 0; nj < 2; ++nj) {
      b1[nj][0] = *(const bf16x8*)(LB + (2 + nj) * 2048 + aoff);
      b1[nj][1] = *(const bf16x8*)(LB + (2 + nj) * 2048 + (aoff ^ 64));
    }
    SA(buf ^ 1, 1, tA);
    BAR();
    __builtin_amdgcn_s_setprio(1);
    #pragma unroll
    for (int kk = 0; kk < 2; ++kk)
      #pragma unroll
      for (int mi = 0; mi < 4; ++mi)
        #pragma unroll
        for (int nj = 0; nj < 2; ++nj)
          acc[mi][2 + nj] = __builtin_amdgcn_mfma_f32_16x16x32_bf16(
              a0[mi][kk], b1[nj][kk], acc[mi][2 + nj], 0, 0, 0);
    __builtin_amdgcn_s_setprio(0);
    BAR();

    // ---- P3: a1 reads; stage tile+2 B-ht0 into this buf (freed after P2)
    #pragma unroll
    for (int mi = 0; mi < 4; ++mi) {
      a1[mi][0] = *(const bf16x8*)(LA + 8192 + mi * 2048 + aoff);
      a1[mi][1] = *(const bf16x8*)(LA + 8192 + mi * 2048 + (aoff ^ 64));
    }
    SB(buf, 0, tB);
    BAR();
    __builtin_amdgcn_s_setprio(1);
    #pragma unroll
    for (int kk = 0; kk < 2; ++kk)
      #pragma unroll
      for (int mi = 0; mi < 4; ++mi)
        #pragma unroll
        for (int nj = 0; nj < 2; ++nj)
          acc[4 + mi][2 + nj] = __builtin_amdgcn_mfma_f32_16x16x32_bf16(
              a1[mi][kk], b1[nj][kk], acc[4 + mi][2 + nj], 0, 0, 0);
    __builtin_amdgcn_s_setprio(0);
    BAR();

    // ---- P4: stage tile+2 B-ht1; MFMA; counted wait (2 ht in flight)
    SB(buf, 1, tB);
    BAR();
    __builtin_amdgcn_s_setprio(1);
    #pragma unroll
    for (int kk = 0; kk < 2; ++kk)
      #pragma unroll
      for (int mi = 0; mi < 4; ++mi)
        #pragma unroll
        for (int nj = 0; nj < 2; ++nj)
          acc[4 + mi][nj] = __builtin_amdgcn_mfma_f32_16x16x32_bf16(
              a1[mi][kk], b0[nj][kk], acc[4 + mi][nj], 0, 0, 0);
    __builtin_amdgcn_s_setprio(0);
    WAITV(4);
    BAR();
  };

  // prologue: tile0 fully (8 loads), tile1 B halves (4 loads); drain tile0.
  SB(0, 0, 0); SB(0, 1, 0);
  SA(0, 0, 0); SA(0, 1, 0);
  SB(1, 0, 1); SB(1, 1, 1);
  WAITV(4);
  BAR();

  #pragma unroll 1
  for (int t = 0; t < KT; t += 2) {
    const int t2 = (t + 2 < KT) ? t + 2 : KT - 1;
    const int t3 = (t + 3 < KT) ? t + 3 : KT - 1;
    HG(0, t + 1, t2);  // compute t   (buf0); stage A(t+1), B(t+2)
    HG(1, t2,    t3);  // compute t+1 (buf1); stage A(t+2), B(t+3)
  }

  const int crow = (lane >> 4) * 4;
  const int ccol = lane & 15;
  if constexpr (MODE == 0) {
    float* oe = (float*)outp + (size_t)e * 1024 * (NBY * 256);
    #pragma unroll
    for (int mi = 0; mi < 8; ++mi)
      #pragma unroll
      for (int nj = 0; nj < 4; ++nj)
        #pragma unroll
        for (int j = 0; j < 4; ++j) {
          const int row = bm + wrm + mi * 16 + crow + j;
          const int col = bnn + wcn + nj * 16 + ccol;
          oe[(size_t)row * (NBY * 256) + col] = acc[mi][nj][j];
        }
  } else {
    // silu-pair: frag nj=2p is gate cols, nj=2p+1 the matching up cols
    unsigned short* he = (unsigned short*)outp + (size_t)e * 1024 * (NBY * 128);
    const int hcb = by * 128 + (wcn >> 1);
    #pragma unroll
    for (int mi = 0; mi < 8; ++mi)
      #pragma unroll
      for (int p = 0; p < 2; ++p)
        #pragma unroll
        for (int j = 0; j < 4; ++j) {
          const float g = acc[mi][2 * p][j];
          const float u = acc[mi][2 * p + 1][j];
          const float sv = g / (1.0f + __expf(-g)) * u;
          const int row = bm + wrm + mi * 16 + crow + j;
          const int col = hcb + p * 16 + ccol;
          he[(size_t)row * (NBY * 128) + col] = f2bf(sv);
        }
  }
}

// ---------------------------------------------------------------------------
extern "C" void kernel_launch(void* const* d_in, const int* in_sizes, int n_in,
                              void* d_out, int out_size, void* d_ws, size_t ws_size,
                              hipStream_t stream) {
  const float* x    = (const float*)d_in[0];  // [E][T][H]
  const float* gate = (const float*)d_in[1];  // [E][H][I]
  const float* up   = (const float*)d_in[2];  // [E][H][I]
  const float* down = (const float*)d_in[3];  // [E][I][H]
  float* out = (float*)d_out;                 // [E][T][H]

  // workspace (bf16): x_bf [E][T][H], wcat [E][2I][H] (g/u 16-col interleave),
  // dT [E][H][I], h [E][T][I].
  unsigned short* x_bf = (unsigned short*)d_ws;
  unsigned short* wcat = x_bf + (size_t)NE * NT * NH;
  unsigned short* dT   = wcat + (size_t)NE * NI2 * NH;
  unsigned short* hb   = dT   + (size_t)NE * NH * NI;

  cvt_bf16<<<2048, 256, 0, stream>>>(x, x_bf, NE * NT * NH / 8);

  transpose_cvt<<<dim3(NI / 64, NH / 64, NE), 256, 0, stream>>>(
      gate, wcat, NH, NI, (long)NI2 * NH, 1, 0);
  transpose_cvt<<<dim3(NI / 64, NH / 64, NE), 256, 0, stream>>>(
      up, wcat, NH, NI, (long)NI2 * NH, 1, 16);
  transpose_cvt<<<dim3(NH / 64, NI / 64, NE), 256, 0, stream>>>(
      down, dT, NI, NH, (long)NH * NI, 0, 0);

  // GEMM1: [1024 x 2816] = x_bf @ wcat^T, fused silu-pair -> h bf16. 352 blocks.
  gemm_8ph<11, NH, 1><<<NE * 11 * 4, 512, 0, stream>>>(x_bf, wcat, hb);
  // GEMM2: [1024 x 2048] = h @ dT^T -> out f32. 256 blocks = 1/CU exactly.
  gemm_8ph<8, NI, 0><<<NE * 8 * 4, 512, 0, stream>>>(hb, dT, out);
}